// Round 17
// baseline (369.838 us; speedup 1.0000x reference)
//
#include <hip/hip_runtime.h>
#include <stdint.h>

#define DIM   2048
#define NSLOT 64
#define MDIM  512
#define TINV  10.0f

typedef __attribute__((ext_vector_type(4))) float     f32x4;
typedef __attribute__((ext_vector_type(8))) _Float16  half8;

#define MFMA16(a,b,c) __builtin_amdgcn_mfma_f32_16x16x32_f16((a),(b),(c),0,0,0)
#define AS1 __attribute__((address_space(1)))
#define AS3 __attribute__((address_space(3)))

// ---------------------------------------------------------------------------
// ws layout (bytes) — IDENTICAL to rounds 15/16 (prep validated):
//   W2F  [32ch] x 24576 B — fragment-packed W2, K=64 chunks, padded to 24 KB
//   W3T  [2048][64] f16
//   h    [64] f32
//   tpart[8][512] f32
// ---------------------------------------------------------------------------
#define OFF_W2F   0
#define OFF_W3T   1310720
#define OFF_H     1572864
#define OFF_TPART 1573120

__device__ __forceinline__ size_t w2f_idx(int row, int k, int lvl) {
    const int t  = row >> 4, ar = row & 15;
    const int ch = k >> 6, ks = (k >> 5) & 1, kg = (k >> 3) & 3, e = k & 7;
    return (size_t)ch * 12288 +
           ((size_t)(((t * 2 + ks) * 2 + lvl) * 64) + kg * 16 + ar) * 8 + e;
}

// ===================== merged prep kernel (w2 | w3t | t) ====================
// (byte-identical to rounds 15/16, validated)

__global__ __launch_bounds__(256) void prep_all(
    const float* __restrict__ memory, const float* __restrict__ key_w,
    const float* __restrict__ value_w, const float* __restrict__ gate_w,
    _Float16* __restrict__ W2F, _Float16* __restrict__ W3T,
    float* __restrict__ tpart)
{
    const int tid = threadIdx.x;
    const int c = blockIdx.x;
    const int role = blockIdx.y;

    if (role == 17) {                       // ---- prep_t ----
        const int b = c;
        float a0 = 0.f, a1 = 0.f;
        for (int d = b * 256; d < b * 256 + 256; ++d) {
            const float gv = gate_w[DIM + d];
            a0 = fmaf(value_w[(size_t)d * MDIM + tid], gv, a0);
            a1 = fmaf(value_w[(size_t)d * MDIM + tid + 256], gv, a1);
        }
        tpart[b * 512 + tid] = a0;
        tpart[b * 512 + tid + 256] = a1;
        return;
    }

    if (role < 9) {                         // ---- prep_w2 ----
        const int g = role;
        const int k = c * 256 + tid;
        if (g == 8) {
            float v = gate_w[k];
            _Float16 ph = (_Float16)v;
            _Float16 pl = (_Float16)(v - (float)ph);
            W2F[w2f_idx(64, k, 0)] = ph;
            W2F[w2f_idx(64, k, 1)] = pl;
            for (int r = 65; r < 80; ++r) {
                W2F[w2f_idx(r, k, 0)] = (_Float16)0.f;
                W2F[w2f_idx(r, k, 1)] = (_Float16)0.f;
            }
            return;
        }
        __shared__ __align__(16) float mem_s[8 * MDIM];
        for (int i = tid; i < 8 * MDIM; i += 256)
            mem_s[i] = memory[g * 8 * MDIM + i];
        __syncthreads();

        const f32x4* ms4 = (const f32x4*)mem_s;
        float acc[8] = {};
        for (int m4 = 0; m4 < MDIM / 4; ++m4) {
            const float kw0 = key_w[(size_t)(m4 * 4 + 0) * DIM + k];
            const float kw1 = key_w[(size_t)(m4 * 4 + 1) * DIM + k];
            const float kw2 = key_w[(size_t)(m4 * 4 + 2) * DIM + k];
            const float kw3 = key_w[(size_t)(m4 * 4 + 3) * DIM + k];
            #pragma unroll
            for (int i = 0; i < 8; ++i) {
                const f32x4 mv = ms4[i * (MDIM / 4) + m4];
                acc[i] = fmaf(mv.x, kw0, acc[i]);
                acc[i] = fmaf(mv.y, kw1, acc[i]);
                acc[i] = fmaf(mv.z, kw2, acc[i]);
                acc[i] = fmaf(mv.w, kw3, acc[i]);
            }
        }
        #pragma unroll
        for (int i = 0; i < 8; ++i) {
            float v = acc[i];
            _Float16 ph = (_Float16)v;
            _Float16 pl = (_Float16)(v - (float)ph);
            W2F[w2f_idx(g * 8 + i, k, 0)] = ph;
            W2F[w2f_idx(g * 8 + i, k, 1)] = pl;
        }
        return;
    }

    {                                       // ---- prep_w3t ----
        const int g = role - 9;
        const int d = c * 256 + tid;
        __shared__ __align__(16) float mem_s2[8 * MDIM];
        for (int i = tid; i < 8 * MDIM; i += 256)
            mem_s2[i] = memory[g * 8 * MDIM + i];
        __syncthreads();

        const f32x4* ms4 = (const f32x4*)mem_s2;
        const f32x4* vp = (const f32x4*)(value_w + (size_t)d * MDIM);
        float acc[8] = {};
        for (int m4 = 0; m4 < MDIM / 4; ++m4) {
            const f32x4 v = vp[m4];
            #pragma unroll
            for (int i = 0; i < 8; ++i) {
                const f32x4 mv = ms4[i * (MDIM / 4) + m4];
                acc[i] = fmaf(mv.x, v.x, acc[i]);
                acc[i] = fmaf(mv.y, v.y, acc[i]);
                acc[i] = fmaf(mv.z, v.z, acc[i]);
                acc[i] = fmaf(mv.w, v.w, acc[i]);
            }
        }
        #pragma unroll
        for (int i = 0; i < 8; ++i)
            W3T[(size_t)d * NSLOT + g * 8 + i] = (_Float16)acc[i];
    }
}

__global__ __launch_bounds__(512) void prep_h(
    const float* __restrict__ memory, const float* __restrict__ tpart,
    float* __restrict__ h)
{
    __shared__ float ts[512];
    const int tid = threadIdx.x;
    float s = 0.f;
    #pragma unroll
    for (int b = 0; b < 8; ++b) s += tpart[b * 512 + tid];
    ts[tid] = s;
    __syncthreads();
    const int lane = tid & 63, w = tid >> 6;
    #pragma unroll
    for (int q = 0; q < 8; ++q) {
        const int n = w * 8 + q;
        float p = 0.f;
        for (int m = lane; m < MDIM; m += 64)
            p = fmaf(memory[(size_t)n * MDIM + m], ts[m], p);
        #pragma unroll
        for (int off = 32; off; off >>= 1) p += __shfl_xor(p, off);
        if (lane == 0) h[n] = p;
    }
}

// ============================ fused kernel =================================
// MAX-TLP design: block = 16 rows, 256 thr / 4 waves, grid 2048, LDS ~5.5 KB,
// launch_bounds(256,6) -> target 6 blocks/CU = 24 waves/CU of independent
// streams (the one regime never tested; all prior rounds were 4-16 waves/CU).
//  - phase A: n-split — wave w owns slot-tile w (16 slots), FULL K; acc is a
//    single f32x4; JIT loads (x from HBM, W2F fragments L2-direct, validated
//    addressing); NO barriers in the loop. Gate g1-dot rides in wave 0's
//    loop on the already-loaded x frags (+ broadcast gate_w loads).
//  - softmax: one 3 KB LDS exchange, wave 0, R16-verbatim math.
//  - phase B: R5/R16-verbatim swapped-MFMA, wave w = d-quarter, global x/out.

__global__ __launch_bounds__(256, 6) void fused_kernel(
    const float* __restrict__ x,
    const _Float16* __restrict__ W2F,
    const _Float16* __restrict__ W3T,
    const float* __restrict__ h, const float* __restrict__ gate_w,
    const float* __restrict__ gate_b, float* __restrict__ out)
{
    __shared__ __align__(16) float ppart[3][64][4];   // 3 KB (waves 1-3 scores)
    __shared__ __align__(16) _Float16 attn_s[16][72]; // 2.25 KB
    __shared__ float xg[16];
    __shared__ float gate_s[16];

    const int tid  = threadIdx.x;
    const int lane = tid & 63;
    const int w    = tid >> 6;          // wave 0..3 = slot-tile (A) / d-quarter (B)
    const int ar   = lane & 15;
    const int kg   = lane >> 4;
    const size_t row0 = (size_t)blockIdx.x * 16;

    // ---- phase A: scores for slot-tile w, full K, no barriers ----
    f32x4 acc = {0.f, 0.f, 0.f, 0.f};
    float gp = 0.f;
    const float* xr = x + (row0 + ar) * DIM + kg * 8;

    #pragma unroll 4
    for (int s = 0; s < 64; ++s) {
        const f32x4 xa = *(const f32x4*)(xr + s * 32);
        const f32x4 xb = *(const f32x4*)(xr + s * 32 + 4);
        // W2 fragment (R16-validated addressing): ch = s>>1, ks = s&1, t = w
        const _Float16* p = W2F + (size_t)(s >> 1) * 12288
                          + (size_t)((w * 2 + (s & 1)) * 2) * 512 + lane * 8;
        const half8 bh = *(const half8*)p;
        const half8 bl = *(const half8*)(p + 512);
        const float xf[8] = {xa.x, xa.y, xa.z, xa.w, xb.x, xb.y, xb.z, xb.w};
        _Float16 hh[8], ll[8];
        #pragma unroll
        for (int u = 0; u < 8; ++u) {
            hh[u] = (_Float16)xf[u];
            ll[u] = (_Float16)(xf[u] - (float)hh[u]);
        }
        const half8 ah = {hh[0], hh[1], hh[2], hh[3], hh[4], hh[5], hh[6], hh[7]};
        const half8 al = {ll[0], ll[1], ll[2], ll[3], ll[4], ll[5], ll[6], ll[7]};
        acc = MFMA16(ah, bh, acc);
        acc = MFMA16(al, bh, acc);
        acc = MFMA16(ah, bl, acc);
        if (w == 0) {   // gate g1-dot on the same x frags (wave-uniform branch)
            const f32x4 g0 = *(const f32x4*)(gate_w + s * 32 + kg * 8);
            const f32x4 g1 = *(const f32x4*)(gate_w + s * 32 + kg * 8 + 4);
            gp = fmaf(xa.x, g0.x, gp); gp = fmaf(xa.y, g0.y, gp);
            gp = fmaf(xa.z, g0.z, gp); gp = fmaf(xa.w, g0.w, gp);
            gp = fmaf(xb.x, g1.x, gp); gp = fmaf(xb.y, g1.y, gp);
            gp = fmaf(xb.z, g1.z, gp); gp = fmaf(xb.w, g1.w, gp);
        }
    }

    if (w == 0) {
        // reduce gate dot over kg groups (lanes ar, ar+16, ar+32, ar+48)
        gp += __shfl_xor(gp, 16);
        gp += __shfl_xor(gp, 32);
        if (kg == 0) xg[ar] = gp;
    } else {
        *(f32x4*)&ppart[w - 1][lane][0] = acc;
    }
    __syncthreads();

    // ---- softmax + gate (wave 0; R16-verbatim math on sc[t]) ----
    if (w == 0) {
        f32x4 sc[4];
        sc[0] = acc;
        #pragma unroll
        for (int t = 1; t < 4; ++t) sc[t] = *(const f32x4*)&ppart[t - 1][lane][0];

        float hl[4];
        #pragma unroll
        for (int t = 0; t < 4; ++t) hl[t] = h[t * 16 + ar];
        const float gb = gate_b[0];

        #pragma unroll
        for (int j = 0; j < 4; ++j) {
            float m = fmaxf(fmaxf(sc[0][j], sc[1][j]), fmaxf(sc[2][j], sc[3][j]));
            #pragma unroll
            for (int off = 1; off < 16; off <<= 1) m = fmaxf(m, __shfl_xor(m, off));
            float p[4];
            float sum = 0.f;
            #pragma unroll
            for (int t = 0; t < 4; ++t) { p[t] = __expf((sc[t][j] - m) * TINV); sum += p[t]; }
            #pragma unroll
            for (int off = 1; off < 16; off <<= 1) sum += __shfl_xor(sum, off);
            const float inv = 1.f / sum;
            const int row = kg * 4 + j;
            float gpp = 0.f;
            #pragma unroll
            for (int t = 0; t < 4; ++t) {
                const float a = p[t] * inv;
                attn_s[row][t * 16 + ar] = (_Float16)a;
                gpp = fmaf(a, hl[t], gpp);
            }
            #pragma unroll
            for (int off = 1; off < 16; off <<= 1) gpp += __shfl_xor(gpp, off);
            if (ar == 0)
                gate_s[row] = 1.f / (1.f + __expf(-(xg[row] + gpp + gb)));
        }
    }
    __syncthreads();

    // ---- phase B: wave w covers d in [w*512, w*512+512), 32 d-tiles ----
    // (R5/R16-validated swapped-operand MFMA + direct float4 mix/store)
    const half8 a0 = *(const half8*)(&attn_s[ar][kg * 8]);
    const half8 a1 = *(const half8*)(&attn_s[ar][kg * 8 + 32]);
    const float g = gate_s[ar];
    const _Float16* w3base = W3T + (size_t)(w * 512 + ar) * NSLOT + kg * 8;
    const size_t rowoff = (row0 + ar) * DIM + w * 512 + kg * 4;
    const float* xp = x + rowoff;
    float* op = out + rowoff;

    half8 qb0[4], qb1[4];
    #pragma unroll
    for (int s = 0; s < 4; ++s) {
        const _Float16* bp = w3base + (size_t)s * 16 * NSLOT;
        qb0[s] = *(const half8*)bp;
        qb1[s] = *(const half8*)(bp + 32);
    }

    #pragma unroll 4
    for (int dt = 0; dt < 32; ++dt) {
        const int s = dt & 3;
        f32x4 r = {0.f, 0.f, 0.f, 0.f};
        r = MFMA16(qb0[s], a0, r);
        r = MFMA16(qb1[s], a1, r);
        int nt = dt + 4; if (nt > 31) nt = 31;      // clamped prefetch
        const _Float16* bp = w3base + (size_t)nt * 16 * NSLOT;
        qb0[s] = *(const half8*)bp;
        qb1[s] = *(const half8*)(bp + 32);
        const f32x4 xv = *(const f32x4*)(xp + dt * 16);
        f32x4 o;
        o.x = fmaf(g, xv.x - r.x, r.x);
        o.y = fmaf(g, xv.y - r.y, r.y);
        o.z = fmaf(g, xv.z - r.z, r.z);
        o.w = fmaf(g, xv.w - r.w, r.w);
        *(f32x4*)(op + dt * 16) = o;
    }
}

// ================================ launch ===================================

extern "C" void kernel_launch(void* const* d_in, const int* in_sizes, int n_in,
                              void* d_out, int out_size, void* d_ws, size_t ws_size,
                              hipStream_t stream) {
    (void)in_sizes; (void)n_in; (void)out_size; (void)ws_size;
    const float* x       = (const float*)d_in[0];
    const float* memory  = (const float*)d_in[1];
    const float* key_w   = (const float*)d_in[2];
    const float* value_w = (const float*)d_in[3];
    const float* gate_w  = (const float*)d_in[4];
    const float* gate_b  = (const float*)d_in[5];
    float* out = (float*)d_out;

    char* wsb = (char*)d_ws;                       // needs ~1.6 MB
    _Float16* W2F = (_Float16*)(wsb + OFF_W2F);
    _Float16* W3T = (_Float16*)(wsb + OFF_W3T);
    float*    h   = (float*)(wsb + OFF_H);
    float*    tpt = (float*)(wsb + OFF_TPART);

    prep_all<<<dim3(8, 18), 256, 0, stream>>>(memory, key_w, value_w, gate_w,
                                              W2F, W3T, tpt);
    prep_h  <<<1, 512, 0, stream>>>(memory, tpt, h);

    fused_kernel<<<2048, 256, 0, stream>>>(x, W2F, W3T, h, gate_w, gate_b, out);
}

// Round 18
// 264.905 us; speedup vs baseline: 1.3961x; 1.3961x over previous
//
#include <hip/hip_runtime.h>
#include <stdint.h>

#define DIM   2048
#define NSLOT 64
#define MDIM  512
#define TINV  10.0f

typedef __attribute__((ext_vector_type(4))) float     f32x4;
typedef __attribute__((ext_vector_type(8))) _Float16  half8;

#define MFMA16(a,b,c) __builtin_amdgcn_mfma_f32_16x16x32_f16((a),(b),(c),0,0,0)
#define AS1 __attribute__((address_space(1)))
#define AS3 __attribute__((address_space(3)))

// ---------------------------------------------------------------------------
// ws layout (bytes) — IDENTICAL to round 15 (prep validated):
//   W2F  [32ch] x 24576 B — fragment-packed W2, K=64 chunks, padded to 24 KB
//   W3T  [2048][64] f16
//   h    [64] f32
//   tpart[8][512] f32
// ---------------------------------------------------------------------------
#define OFF_W2F   0
#define OFF_W3T   1310720
#define OFF_H     1572864
#define OFF_TPART 1573120

__device__ __forceinline__ size_t w2f_idx(int row, int k, int lvl) {
    const int t  = row >> 4, ar = row & 15;
    const int ch = k >> 6, ks = (k >> 5) & 1, kg = (k >> 3) & 3, e = k & 7;
    return (size_t)ch * 12288 +
           ((size_t)(((t * 2 + ks) * 2 + lvl) * 64) + kg * 16 + ar) * 8 + e;
}

// ===================== merged prep kernel (w2 | w3t | t) ====================
// (byte-identical to rounds 15-17, validated)

__global__ __launch_bounds__(256) void prep_all(
    const float* __restrict__ memory, const float* __restrict__ key_w,
    const float* __restrict__ value_w, const float* __restrict__ gate_w,
    _Float16* __restrict__ W2F, _Float16* __restrict__ W3T,
    float* __restrict__ tpart)
{
    const int tid = threadIdx.x;
    const int c = blockIdx.x;
    const int role = blockIdx.y;

    if (role == 17) {                       // ---- prep_t ----
        const int b = c;
        float a0 = 0.f, a1 = 0.f;
        for (int d = b * 256; d < b * 256 + 256; ++d) {
            const float gv = gate_w[DIM + d];
            a0 = fmaf(value_w[(size_t)d * MDIM + tid], gv, a0);
            a1 = fmaf(value_w[(size_t)d * MDIM + tid + 256], gv, a1);
        }
        tpart[b * 512 + tid] = a0;
        tpart[b * 512 + tid + 256] = a1;
        return;
    }

    if (role < 9) {                         // ---- prep_w2 ----
        const int g = role;
        const int k = c * 256 + tid;
        if (g == 8) {
            float v = gate_w[k];
            _Float16 ph = (_Float16)v;
            _Float16 pl = (_Float16)(v - (float)ph);
            W2F[w2f_idx(64, k, 0)] = ph;
            W2F[w2f_idx(64, k, 1)] = pl;
            for (int r = 65; r < 80; ++r) {
                W2F[w2f_idx(r, k, 0)] = (_Float16)0.f;
                W2F[w2f_idx(r, k, 1)] = (_Float16)0.f;
            }
            return;
        }
        __shared__ __align__(16) float mem_s[8 * MDIM];
        for (int i = tid; i < 8 * MDIM; i += 256)
            mem_s[i] = memory[g * 8 * MDIM + i];
        __syncthreads();

        const f32x4* ms4 = (const f32x4*)mem_s;
        float acc[8] = {};
        for (int m4 = 0; m4 < MDIM / 4; ++m4) {
            const float kw0 = key_w[(size_t)(m4 * 4 + 0) * DIM + k];
            const float kw1 = key_w[(size_t)(m4 * 4 + 1) * DIM + k];
            const float kw2 = key_w[(size_t)(m4 * 4 + 2) * DIM + k];
            const float kw3 = key_w[(size_t)(m4 * 4 + 3) * DIM + k];
            #pragma unroll
            for (int i = 0; i < 8; ++i) {
                const f32x4 mv = ms4[i * (MDIM / 4) + m4];
                acc[i] = fmaf(mv.x, kw0, acc[i]);
                acc[i] = fmaf(mv.y, kw1, acc[i]);
                acc[i] = fmaf(mv.z, kw2, acc[i]);
                acc[i] = fmaf(mv.w, kw3, acc[i]);
            }
        }
        #pragma unroll
        for (int i = 0; i < 8; ++i) {
            float v = acc[i];
            _Float16 ph = (_Float16)v;
            _Float16 pl = (_Float16)(v - (float)ph);
            W2F[w2f_idx(g * 8 + i, k, 0)] = ph;
            W2F[w2f_idx(g * 8 + i, k, 1)] = pl;
        }
        return;
    }

    {                                       // ---- prep_w3t ----
        const int g = role - 9;
        const int d = c * 256 + tid;
        __shared__ __align__(16) float mem_s2[8 * MDIM];
        for (int i = tid; i < 8 * MDIM; i += 256)
            mem_s2[i] = memory[g * 8 * MDIM + i];
        __syncthreads();

        const f32x4* ms4 = (const f32x4*)mem_s2;
        const f32x4* vp = (const f32x4*)(value_w + (size_t)d * MDIM);
        float acc[8] = {};
        for (int m4 = 0; m4 < MDIM / 4; ++m4) {
            const f32x4 v = vp[m4];
            #pragma unroll
            for (int i = 0; i < 8; ++i) {
                const f32x4 mv = ms4[i * (MDIM / 4) + m4];
                acc[i] = fmaf(mv.x, v.x, acc[i]);
                acc[i] = fmaf(mv.y, v.y, acc[i]);
                acc[i] = fmaf(mv.z, v.z, acc[i]);
                acc[i] = fmaf(mv.w, v.w, acc[i]);
            }
        }
        #pragma unroll
        for (int i = 0; i < 8; ++i)
            W3T[(size_t)d * NSLOT + g * 8 + i] = (_Float16)acc[i];
    }
}

__global__ __launch_bounds__(512) void prep_h(
    const float* __restrict__ memory, const float* __restrict__ tpart,
    float* __restrict__ h)
{
    __shared__ float ts[512];
    const int tid = threadIdx.x;
    float s = 0.f;
    #pragma unroll
    for (int b = 0; b < 8; ++b) s += tpart[b * 512 + tid];
    ts[tid] = s;
    __syncthreads();
    const int lane = tid & 63, w = tid >> 6;
    #pragma unroll
    for (int q = 0; q < 8; ++q) {
        const int n = w * 8 + q;
        float p = 0.f;
        for (int m = lane; m < MDIM; m += 64)
            p = fmaf(memory[(size_t)n * MDIM + m], ts[m], p);
        #pragma unroll
        for (int off = 32; off; off >>= 1) p += __shfl_xor(p, off);
        if (lane == 0) h[n] = p;
    }
}

// ============================ fused kernel =================================
// R15 base (best wall, validated) + three scheduling-only overlaps:
//  1. Phase B rotation deepened 4 -> 8 slots (VGPRs are free at 1 block/CU).
//  2. First 8 phase-B load groups issued BEFORE the combine barriers; the
//     combine barriers drain lgkmcnt ONLY (raw s_barrier, no vmcnt drain),
//     so those loads stay in flight while softmax runs.
//  3. Bijective XCD swizzle on blockIdx (512 % 8 == 0).

__global__ __launch_bounds__(512) void fused_kernel(
    const float* __restrict__ x,
    const _Float16* __restrict__ W2F,
    const _Float16* __restrict__ W3T,
    const float* __restrict__ h, const float* __restrict__ gate_b,
    float* __restrict__ out)
{
    __shared__ __align__(16) _Float16 w2s[2][12288];        // 48 KB (incl pad)
    __shared__ __align__(16) float    xs[4][4096];          // 64 KB x ring
    __shared__ __align__(16) float ppart[4 * 5 * 64 * 4];   // 20 KB partials
    __shared__ __align__(16) _Float16 attn_s[4][16][72];    // 9 KB
    __shared__ float gate_s[4][16];

    const int tid  = threadIdx.x;
    const int lane = tid & 63;
    const int w    = tid >> 6;          // wave 0..7
    const int mt   = w & 3;             // m-tile
    const int kh   = w >> 2;            // k-half (kstep within chunk)
    const int arow = lane & 15;
    const int kg   = lane >> 4;
    const int bid  = (int)blockIdx.x;
    const int swz  = (bid & 7) * 64 + (bid >> 3);   // XCD-bijective (512%8==0)
    const size_t row0 = (size_t)swz * 64;

    f32x4 acc[5];
    {   f32x4 z = {0.f, 0.f, 0.f, 0.f};
        #pragma unroll
        for (int t = 0; t < 5; ++t) acc[t] = z; }

    // ---- DMA: W2 chunk image (1536 granules, 3/thread, linear both sides) ----
    auto dmaW2 = [&](int ch, int buf) {
        const char* base = (const char*)W2F + (size_t)ch * 24576;
        char* db = (char*)&w2s[buf][0];
        #pragma unroll
        for (int i = 0; i < 3; ++i)
            __builtin_amdgcn_global_load_lds(
                (const AS1 void*)(base + (size_t)(i * 512 + tid) * 16),
                (AS3 void*)(db + (size_t)(i * 512 + w * 64) * 16), 16, 0, 0);
    };
    // ---- DMA: x chunk [64 rows][64 k] (1024 granules, 2/thread),
    //      linear dest, XOR-swizzled source granule ----
    auto dmaX = [&](int ch, int buf) {
        char* db = (char*)&xs[buf][0];
        #pragma unroll
        for (int i = 0; i < 2; ++i) {
            const int gid = i * 512 + tid;
            const int row = gid >> 4, gq = gid & 15;
            const char* src = (const char*)(x + (size_t)(row0 + row) * DIM + ch * 64)
                              + ((gq ^ (row & 7)) << 4);
            __builtin_amdgcn_global_load_lds(
                (const AS1 void*)src,
                (AS3 void*)(db + (size_t)(i * 512 + w * 64) * 16), 16, 0, 0);
        }
    };

    auto compute_chunk = [&](int xbuf, int wbuf) {
        const int row = mt * 16 + arow;
        const char* xrb = (const char*)&xs[xbuf][0] + row * 256;
        const int g0 = kh * 8 + kg * 2;
        const f32x4 xa = *(const f32x4*)(xrb + ((g0 ^ (arow & 7)) << 4));
        const f32x4 xb = *(const f32x4*)(xrb + (((g0 + 1) ^ (arow & 7)) << 4));
        const float xf[8] = {xa.x, xa.y, xa.z, xa.w, xb.x, xb.y, xb.z, xb.w};
        _Float16 hh[8], ll[8];
        #pragma unroll
        for (int u = 0; u < 8; ++u) {
            hh[u] = (_Float16)xf[u];
            ll[u] = (_Float16)(xf[u] - (float)hh[u]);
        }
        const half8 ah = {hh[0], hh[1], hh[2], hh[3], hh[4], hh[5], hh[6], hh[7]};
        const half8 al = {ll[0], ll[1], ll[2], ll[3], ll[4], ll[5], ll[6], ll[7]};
        #pragma unroll
        for (int t = 0; t < 5; ++t) {
            const _Float16* p = &w2s[wbuf][0] + (size_t)((t * 2 + kh) * 2) * 512 + lane * 8;
            const half8 bh = *(const half8*)p;
            const half8 bl = *(const half8*)(p + 512);
            acc[t] = MFMA16(ah, bh, acc[t]);
            acc[t] = MFMA16(al, bh, acc[t]);
            acc[t] = MFMA16(ah, bl, acc[t]);
        }
    };

    // ---- phase A: 32 chunks; x 4-deep, W2 2-deep, counted vmcnt(7) ----
    dmaW2(0, 0); dmaX(0, 0);
    dmaW2(1, 1); dmaX(1, 1);
    dmaX(2, 2);  dmaX(3, 3);
    #pragma unroll 4
    for (int ch = 0; ch < 32; ++ch) {
        if (ch < 28) asm volatile("s_waitcnt vmcnt(7)" ::: "memory");
        else         asm volatile("s_waitcnt vmcnt(0)" ::: "memory");
        __builtin_amdgcn_s_barrier();            // chunk ch fully in LDS (all waves)
        compute_chunk(ch & 3, ch & 1);
        __builtin_amdgcn_s_barrier();            // all waves done reading bufs
        if (ch + 2 < 32) dmaW2(ch + 2, ch & 1);  // refill just-freed W2 buf
        if (ch + 4 < 32) dmaX(ch + 4, ch & 3);   // refill just-freed x buf
    }

    // ---- phase-B pointer setup + 8-deep prefetch BEFORE the combine ----
    const size_t rbase = row0 + mt * 16;
    const size_t rowoff = (rbase + arow) * DIM + kh * 1024 + kg * 4;
    const float* xp = x + rowoff;
    float* op = out + rowoff;
    const _Float16* w3base = W3T + (size_t)(kh * 1024 + arow) * NSLOT + kg * 8;

    half8 qb0[8], qb1[8];
    f32x4 qx[8];
    #pragma unroll
    for (int s = 0; s < 8; ++s) {
        const _Float16* bp = w3base + (size_t)s * 16 * NSLOT;
        qb0[s] = *(const half8*)bp;
        qb1[s] = *(const half8*)(bp + 32);
        qx[s]  = *(const f32x4*)(xp + s * 16);
    }

    // ---- K-split combine (lgkmcnt-only barriers: phase-B loads survive) ----
    if (kh == 1) {
        #pragma unroll
        for (int t = 0; t < 5; ++t)
            *(f32x4*)(ppart + (size_t)((mt * 5 + t) * 64 + lane) * 4) = acc[t];
    }
    asm volatile("s_waitcnt lgkmcnt(0)\n\ts_barrier" ::: "memory");

    if (kh == 0) {
        #pragma unroll
        for (int t = 0; t < 5; ++t)
            acc[t] += *(const f32x4*)(ppart + (size_t)((mt * 5 + t) * 64 + lane) * 4);

        // ---- in-register softmax + gate (R15 verbatim) ----
        float hl[4];
        #pragma unroll
        for (int t = 0; t < 4; ++t) hl[t] = h[t * 16 + arow];
        const float gb = gate_b[0];

        #pragma unroll
        for (int j = 0; j < 4; ++j) {
            float m = fmaxf(fmaxf(acc[0][j], acc[1][j]), fmaxf(acc[2][j], acc[3][j]));
            #pragma unroll
            for (int off = 1; off < 16; off <<= 1) m = fmaxf(m, __shfl_xor(m, off));
            float p[4];
            float sum = 0.f;
            #pragma unroll
            for (int t = 0; t < 4; ++t) { p[t] = __expf((acc[t][j] - m) * TINV); sum += p[t]; }
            #pragma unroll
            for (int off = 1; off < 16; off <<= 1) sum += __shfl_xor(sum, off);
            const float inv = 1.f / sum;
            float gp = 0.f;
            #pragma unroll
            for (int t = 0; t < 4; ++t) {
                const float a = p[t] * inv;
                attn_s[mt][kg * 4 + j][t * 16 + arow] = (_Float16)a;
                gp = fmaf(a, hl[t], gp);
            }
            #pragma unroll
            for (int off = 1; off < 16; off <<= 1) gp += __shfl_xor(gp, off);
            const float sg = __shfl(acc[4][j], lane & 48);
            if (arow == 0)
                gate_s[mt][kg * 4 + j] = 1.f / (1.f + __expf(-(sg + gp + gb)));
        }
    }
    asm volatile("s_waitcnt lgkmcnt(0)\n\ts_barrier" ::: "memory");

    // ---- phase B: retrieve + mix, 8-deep rotation (math = R15) ----
    const half8 a0 = *(const half8*)(&attn_s[mt][arow][kg * 8]);
    const half8 a1 = *(const half8*)(&attn_s[mt][arow][kg * 8 + 32]);
    const float g = gate_s[mt][arow];

    #pragma unroll 8
    for (int dt = 0; dt < 64; ++dt) {
        const int s = dt & 7;
        f32x4 r = {0.f, 0.f, 0.f, 0.f};
        r = MFMA16(qb0[s], a0, r);
        r = MFMA16(qb1[s], a1, r);
        const f32x4 xv = qx[s];
        int nt = dt + 8; if (nt > 63) nt = 63;
        const _Float16* bp = w3base + (size_t)nt * 16 * NSLOT;
        qb0[s] = *(const half8*)bp;
        qb1[s] = *(const half8*)(bp + 32);
        qx[s]  = *(const f32x4*)(xp + (size_t)nt * 16);
        f32x4 o;
        o.x = fmaf(g, xv.x - r.x, r.x);
        o.y = fmaf(g, xv.y - r.y, r.y);
        o.z = fmaf(g, xv.z - r.z, r.z);
        o.w = fmaf(g, xv.w - r.w, r.w);
        *(f32x4*)(op + dt * 16) = o;
    }
}

// ================================ launch ===================================

extern "C" void kernel_launch(void* const* d_in, const int* in_sizes, int n_in,
                              void* d_out, int out_size, void* d_ws, size_t ws_size,
                              hipStream_t stream) {
    (void)in_sizes; (void)n_in; (void)out_size; (void)ws_size;
    const float* x       = (const float*)d_in[0];
    const float* memory  = (const float*)d_in[1];
    const float* key_w   = (const float*)d_in[2];
    const float* value_w = (const float*)d_in[3];
    const float* gate_w  = (const float*)d_in[4];
    const float* gate_b  = (const float*)d_in[5];
    float* out = (float*)d_out;

    char* wsb = (char*)d_ws;                       // needs ~1.6 MB
    _Float16* W2F = (_Float16*)(wsb + OFF_W2F);
    _Float16* W3T = (_Float16*)(wsb + OFF_W3T);
    float*    h   = (float*)(wsb + OFF_H);
    float*    tpt = (float*)(wsb + OFF_TPART);

    prep_all<<<dim3(8, 18), 256, 0, stream>>>(memory, key_w, value_w, gate_w,
                                              W2F, W3T, tpt);
    prep_h  <<<1, 512, 0, stream>>>(memory, tpt, h);

    fused_kernel<<<512, 512, 0, stream>>>(x, W2F, W3T, h, gate_b, out);
}